// Round 8
// baseline (4646.270 us; speedup 1.0000x reference)
//
#include <hip/hip_runtime.h>

// PointNetSAModule on MI355X (gfx950).
// B=16, N=8192, CIN=64, S=1024, K=32, radius=0.2, MLP 67->64->64->128, eps=1e-5.
// Inputs/outputs float32 (proven R4). ws footprint = 1,088,512 B (proven safe).
//
// R7 -> R8 (both driven by VGPR_Count evidence of spills):
//  * fps: coords live in LDS (112 B/thread regions, conflict-free b128 reads) --
//    the allocator spilled/remat'd register-resident coords in R5/R6/R7.
//  * mlp: outer-product restructure -- y[64] accumulators (static idx -> regs),
//    activation pairs consumed on the fly (no xh[34] array), layers 2/3 fully
//    unrolled over static h1/h2[32]; weights stored column-major.

typedef unsigned short u16;
typedef unsigned int   u32;

#define NB    16
#define NPTS  8192
#define CINF  64
#define NS    1024
#define KK    32
#define NSAMP (NB*NS*KK)   // 524288

typedef _Float16 h2v __attribute__((ext_vector_type(2)));

static __device__ __forceinline__ h2v asH2(u32 x){ union{u32 u; h2v h;} v; v.u=x; return v.h; }
static __device__ __forceinline__ u32 asU32(h2v h){ union{u32 u; h2v h;} v; v.h=h; return v.u; }
static __device__ __forceinline__ u32 packh(float lo, float hi){
  union{ _Float16 h[2]; u32 u; } v;
  v.h[0]=(_Float16)lo; v.h[1]=(_Float16)hi; return v.u;
}
static __device__ __forceinline__ float fdot2(h2v a, h2v b, float c){
#if __has_builtin(__builtin_amdgcn_fdot2)
  return __builtin_amdgcn_fdot2(a,b,c,false);   // v_dot2_f32_f16
#else
  return c + (float)a[0]*(float)b[0] + (float)a[1]*(float)b[1];
#endif
}

// exact-order d^2, matching numpy f32: (dx*dx + dy*dy) + dz*dz, no FMA contraction
static __device__ __forceinline__ float d2_exact(float ax,float ay,float az,float bx,float by,float bz){
  float dx=__fsub_rn(ax,bx), dy=__fsub_rn(ay,by), dz=__fsub_rn(az,bz);
  return __fadd_rn(__fadd_rn(__fmul_rn(dx,dx),__fmul_rn(dy,dy)),__fmul_rn(dz,dz));
}

// ---------------------------------------------------------------- prep ----
// Weights packed f16 pairs, COLUMN-major: WpT[u*C + c] = (W[c][2u], W[c][2u+1])
__global__ void prep_kernel(const float* __restrict__ W0, const float* __restrict__ W1,
                            const float* __restrict__ W2,
                            u32* __restrict__ Wp0, u32* __restrict__ Wp1, u32* __restrict__ Wp2,
                            float* __restrict__ stats)
{
  const int t = threadIdx.x;
  for (int i=t;i<768;i+=256) stats[i]=0.f;
  for (int i=t;i<34*64;i+=256){            // W0 (64,67): u<34, pad j>=67 with 0
    int u = i>>6, c = i&63;
    int j0 = 2*u, j1 = 2*u+1;
    float lo = (j0<67)? W0[c*67+j0] : 0.f;
    float hi = (j1<67)? W0[c*67+j1] : 0.f;
    Wp0[i] = packh(lo,hi);
  }
  for (int i=t;i<32*64;i+=256){            // W1 (64,64): u<32
    int u = i>>6, c = i&63;
    Wp1[i] = packh(W1[c*64+2*u], W1[c*64+2*u+1]);
  }
  for (int i=t;i<32*128;i+=256){           // W2 (128,64): u<32, c<128
    int u = i>>7, c = i&127;
    Wp2[i] = packh(W2[c*64+2*u], W2[c*64+2*u+1]);
  }
}

// ----------------------------------------------------------------- FPS ----
// one block per batch; 1024 threads, 8 CONSECUTIVE points/thread in an LDS
// region of 28 f32 (x0..x7,y0..y7,z0..z7,pad4; 112 B stride -> 2-way banks,
// free). dist[8] loop-carried in regs. 6x ds_read_b128 per thread per step.
__global__ __launch_bounds__(1024,1) void fps_kernel(const float* __restrict__ xyz,
    float* __restrict__ out_xyz)
{
  __shared__ float sc[1024*28];            // 114,688 B
  __shared__ float s_v[2][16];
  __shared__ int   s_i[2][16];
  const int b = blockIdx.x, t = threadIdx.x;
  const float* xb = xyz + (size_t)b*3*NPTS;
  const int tb = t*28;
  #pragma unroll
  for (int i=0;i<8;i++){
    const int idx = 8*t + i;
    sc[tb+i]    = xb[idx];
    sc[tb+8+i]  = xb[NPTS+idx];
    sc[tb+16+i] = xb[2*NPTS+idx];
  }
  float d[8];
  #pragma unroll
  for (int i=0;i<8;i++) d[i]=__builtin_inff();
  __syncthreads();
  float cx = xb[0], cy = xb[NPTS], cz = xb[2*NPTS];   // initial center = point 0
  const int lane = t & 63, wv = t >> 6, l16 = lane & 15;
  for (int step=0; step<NS; step++){
    if (t==0){
      out_xyz[(size_t)(b*3+0)*NS+step]=cx;
      out_xyz[(size_t)(b*3+1)*NS+step]=cy;
      out_xyz[(size_t)(b*3+2)*NS+step]=cz;
    }
    if (step==NS-1) break;
    // 6 vector LDS reads: x[0..7], y[0..7], z[0..7]
    float4 X0 = *(const float4*)&sc[tb];
    float4 X1 = *(const float4*)&sc[tb+4];
    float4 Y0 = *(const float4*)&sc[tb+8];
    float4 Y1 = *(const float4*)&sc[tb+12];
    float4 Z0 = *(const float4*)&sc[tb+16];
    float4 Z1 = *(const float4*)&sc[tb+20];
    float bv=-1.f; int bi=0;
#define UPD(i, PX, PY, PZ) { \
    float d2 = d2_exact(PX,PY,PZ, cx,cy,cz); \
    float nd = fminf(d[i], d2); d[i]=nd; \
    if (nd>bv){ bv=nd; bi=8*t+i; } }
    UPD(0, X0.x, Y0.x, Z0.x)  UPD(1, X0.y, Y0.y, Z0.y)
    UPD(2, X0.z, Y0.z, Z0.z)  UPD(3, X0.w, Y0.w, Z0.w)
    UPD(4, X1.x, Y1.x, Z1.x)  UPD(5, X1.y, Y1.y, Z1.y)
    UPD(6, X1.z, Y1.z, Z1.z)  UPD(7, X1.w, Y1.w, Z1.w)
#undef UPD
    #pragma unroll
    for (int off=1; off<64; off<<=1){    // wave argmax, smallest-index tie-break
      float ov=__shfl_xor(bv,off); int oi=__shfl_xor(bi,off);
      bool take = (ov>bv) || (ov==bv && oi<bi);
      bv=take?ov:bv; bi=take?oi:bi;
    }
    const int p = step&1;                // double-buffered -> single barrier/step
    if (lane==0){ s_v[p][wv]=bv; s_i[p][wv]=bi; }
    __syncthreads();
    bv = s_v[p][l16]; bi = s_i[p][l16];  // 16 wave slots -> lanes, 4-level reduce
    #pragma unroll
    for (int off=1; off<16; off<<=1){
      float ov=__shfl_xor(bv,off); int oi=__shfl_xor(bi,off);
      bool take = (ov>bv) || (ov==bv && oi<bi);
      bv=take?ov:bv; bi=take?oi:bi;
    }
    // winner coords via uniform (broadcast) LDS reads
    const int w = bi, wt = w>>3, wi = w&7, wb = wt*28;
    cx = sc[wb+wi]; cy = sc[wb+8+wi]; cz = sc[wb+16+wi];
  }
}

// ---------------------------------------------------------- ball query ----
// one wave per center; first 32 ascending indices with d2 < 0.04; pad with first.
__global__ __launch_bounds__(256) void ballq_kernel(const float* __restrict__ xyz,
    const float* __restrict__ out_xyz, u16* __restrict__ gidx)
{
  const int gid = blockIdx.x*4 + (threadIdx.x>>6);
  const int lane = threadIdx.x & 63;
  const int b = gid >> 10, s = gid & (NS-1);
  const float* xb = xyz + (size_t)b*3*NPTS;
  const float cx = out_xyz[(size_t)(b*3+0)*NS+s];
  const float cy = out_xyz[(size_t)(b*3+1)*NS+s];
  const float cz = out_xyz[(size_t)(b*3+2)*NS+s];
  u16* out = gidx + (size_t)gid*KK;
  int cnt=0, first=-1;
  for (int base=0; base<NPTS; base+=64){
    const int pidx = base + lane;
    float d2 = d2_exact(cx,cy,cz, xb[pidx], xb[NPTS+pidx], xb[2*NPTS+pidx]);
    bool within = d2 < 0.04f;
    unsigned long long m = __ballot(within);
    if (m){
      if (first<0) first = base + (__ffsll(m)-1);
      int pos = cnt + (int)__popcll(m & ((1ull<<lane)-1ull));
      if (within && pos<KK) out[pos]=(u16)pidx;
      cnt += (int)__popcll(m);
      if (cnt>=KK) break;
    }
  }
  if (first<0) first=0;                  // unreachable (center self-hit)
  for (int posi = cnt + lane; posi < KK; posi += 64) out[posi]=(u16)first;
}

// --------------------------------------------------------------- MLP -----
// STAGE 0: stats of y1 | 1: stats of y2 | 2: stats of y3 + packed (max,min) over K.
// Outer-product form: y[64] register accumulators; input pair consumed on the fly.
template<int STAGE>
__global__ __launch_bounds__(256,2) void mlp_pass(
    const float* __restrict__ xyz, const float* __restrict__ feat,
    const float* __restrict__ out_xyz, const u16* __restrict__ gidx,
    const u32* __restrict__ Wp0, const u32* __restrict__ Wp1, const u32* __restrict__ Wp2,
    const float* __restrict__ affine, float* __restrict__ stats, u32* __restrict__ outMM)
{
  constexpr int TCO = (STAGE==2)?128:64;       // stats channel count
  __shared__ float bins[TCO*2*32];             // 16/32 KB, 32 stripes -> 2-way free

  const int t = threadIdx.x;
  for (int i=t;i<TCO*2*32;i+=256) bins[i]=0.f;
  __syncthreads();

  const int ss = blockIdx.x*256 + t;           // flat (b,s,k)
  const int b = ss >> 15;
  const int s = (ss >> 5) & (NS-1);
  const int g = ((int)gidx[ss]) & (NPTS-1);    // clamp: never OOB
  const float* xb = xyz + (size_t)b*3*NPTS;
  const float* fb = feat + (size_t)b*CINF*NPTS;
  const float cx = out_xyz[(size_t)(b*3+0)*NS+s];
  const float cy = out_xyz[(size_t)(b*3+1)*NS+s];
  const float cz = out_xyz[(size_t)(b*3+2)*NS+s];
  const int r = t & 31;

  float y[64];
  #pragma unroll
  for (int c=0;c<64;c++) y[c]=0.f;

  // ---- layer 1 (67->64), outer product over 34 input pairs ----
  {
    float dx = __fsub_rn(xb[g],        cx);
    float dy = __fsub_rn(xb[NPTS+g],   cy);
    float dz = __fsub_rn(xb[2*NPTS+g], cz);
    u32 p0 = packh(dx,dy);
    u32 p1 = packh(dz, fb[g]);                 // (dz, f0)
    {
      const u32* wc = Wp0;                     // u=0 column
      #pragma unroll
      for (int c=0;c<64;c++) y[c] = fdot2(asH2(p0), asH2(wc[c]), y[c]);
    }
    {
      const u32* wc = Wp0 + 64;                // u=1 column
      #pragma unroll
      for (int c=0;c<64;c++) y[c] = fdot2(asH2(p1), asH2(wc[c]), y[c]);
    }
    float A0 = fb[(size_t)1*NPTS+g];           // f1 (for u=2)
    float A1 = fb[(size_t)2*NPTS+g];           // f2
    #pragma unroll 1
    for (int u=2; u<34; u++){
      u32 pr = packh(A0, A1);
      if (u<33){                               // prefetch next pair (u=33 -> f63,0)
        A0 = fb[(size_t)(2*u-1)*NPTS+g];
        A1 = (u<32)? fb[(size_t)(2*u)*NPTS+g] : 0.f;
      }
      const u32* wc = Wp0 + u*64;
      #pragma unroll
      for (int c=0;c<64;c++) y[c] = fdot2(asH2(pr), asH2(wc[c]), y[c]);
    }
  }

  if constexpr (STAGE==0){
    #pragma unroll
    for (int c=0;c<64;c++){
      atomicAdd(&bins[c*32+r], y[c]);
      atomicAdd(&bins[(64+c)*32+r], __fmul_rn(y[c],y[c]));
    }
  } else {
    u32 h1[32];
    #pragma unroll
    for (int c=0;c<32;c++){
      float z0 = fmaxf(fmaf(y[2*c],   affine[4*c],   affine[4*c+1]), 0.f);
      float z1 = fmaxf(fmaf(y[2*c+1], affine[4*c+2], affine[4*c+3]), 0.f);
      h1[c] = packh(z0,z1);
    }
    // ---- layer 2 (64->64) ----
    #pragma unroll
    for (int c=0;c<64;c++) y[c]=0.f;
    #pragma unroll
    for (int u=0;u<32;u++){
      const u32* wc = Wp1 + u*64;
      #pragma unroll
      for (int c=0;c<64;c++) y[c] = fdot2(asH2(h1[u]), asH2(wc[c]), y[c]);
    }
    if constexpr (STAGE==1){
      #pragma unroll
      for (int c=0;c<64;c++){
        atomicAdd(&bins[c*32+r], y[c]);
        atomicAdd(&bins[(64+c)*32+r], __fmul_rn(y[c],y[c]));
      }
    } else {
      u32 h2[32];
      #pragma unroll
      for (int c=0;c<32;c++){
        float z0 = fmaxf(fmaf(y[2*c],   affine[256+4*c],   affine[256+4*c+1]), 0.f);
        float z1 = fmaxf(fmaf(y[2*c+1], affine[256+4*c+2], affine[256+4*c+3]), 0.f);
        h2[c] = packh(z0,z1);
      }
      // ---- layer 3 (64->128), two halves of 64 to bound register pressure ----
      #pragma unroll 1
      for (int half=0; half<2; half++){
        float z[64];
        #pragma unroll
        for (int c=0;c<64;c++) z[c]=0.f;
        #pragma unroll
        for (int u=0;u<32;u++){
          const u32* wc = Wp2 + u*128 + half*64;
          #pragma unroll
          for (int c=0;c<64;c++) z[c] = fdot2(asH2(h2[u]), asH2(wc[c]), z[c]);
        }
        #pragma unroll
        for (int c=0;c<64;c++){
          const int cc = half*64 + c;
          atomicAdd(&bins[cc*32+r], z[c]);
          atomicAdd(&bins[(128+cc)*32+r], __fmul_rn(z[c],z[c]));
          // packed (f16(z), f16(-z)) -> v_pk_max_f16 reduction over K=32
          u32 pm = packh(z[c], -z[c]);
          #pragma unroll
          for (int off=1; off<32; off<<=1){
            u32 o = __shfl_xor(pm, off);
            pm = asU32(__builtin_elementwise_max(asH2(pm), asH2(o)));
          }
          if ((t&31)==0){
            h2v m = asH2(pm);
            outMM[((size_t)b*128 + cc)*NS + s] = packh((float)m[0], -(float)m[1]);
          }
        }
      }
    }
  }

  __syncthreads();
  if (t < TCO){
    float s1=0.f, s2=0.f;
    #pragma unroll
    for (int q=0;q<32;q++){ s1 += bins[t*32+q]; s2 += bins[(TCO+t)*32+q]; }
    atomicAdd(&stats[STAGE*256 + 2*t],   s1);
    atomicAdd(&stats[STAGE*256 + 2*t+1], s2);
  }
}

// ----------------------------------------------------------- finalize ----
__global__ void finalize_kernel(const float* __restrict__ st, float* __restrict__ af,
                                const float* __restrict__ gamma, const float* __restrict__ beta, int C)
{
  int c = threadIdx.x;
  if (c < C){
    float mean = st[2*c] * (1.f/524288.f);
    float var  = fmaxf(st[2*c+1] * (1.f/524288.f) - mean*mean, 0.f);
    float rstd = 1.f / sqrtf(var + 1e-5f);
    float sc = rstd * gamma[c];
    af[2*c]   = sc;
    af[2*c+1] = beta[c] - mean*sc;
  }
}

// -------------------------------------------------------------- apply ----
// out_feat[i] holds packed f16 (max_k y3, min_k y3); finish BN+relu.
__global__ void apply_kernel(const float* __restrict__ affine, float* __restrict__ outF)
{
  const int i = blockIdx.x*256 + threadIdx.x;      // 16*128*1024 elements
  const int c = (i >> 10) & 127;
  u32 v = ((const u32*)outF)[i];
  h2v h = asH2(v);
  float sc = affine[512+2*c], sh = affine[512+2*c+1];
  float cand = (sc > 0.f) ? (float)h[0] : (float)h[1];
  outF[i] = fmaxf(fmaf(cand, sc, sh), 0.f);
}

// ------------------------------------------------------------- launch ----
extern "C" void kernel_launch(void* const* d_in, const int* in_sizes, int n_in,
                              void* d_out, int out_size, void* d_ws, size_t ws_size,
                              hipStream_t stream)
{
  (void)in_sizes; (void)n_in; (void)out_size; (void)ws_size;
  const float* xyz  = (const float*)d_in[0];
  const float* feat = (const float*)d_in[1];
  const float* W0 = (const float*)d_in[2];
  const float* g0 = (const float*)d_in[3];
  const float* b0 = (const float*)d_in[4];
  const float* W1 = (const float*)d_in[5];
  const float* g1 = (const float*)d_in[6];
  const float* b1 = (const float*)d_in[7];
  const float* W2 = (const float*)d_in[8];
  const float* g2 = (const float*)d_in[9];
  const float* b2 = (const float*)d_in[10];

  char* ws = (char*)d_ws;                      // 1,088,512 B total (proven safe)
  u16*   gidx    = (u16*)  (ws + 0);           // 524288 u16  = 1048576 B
  u32*   Wp0     = (u32*)  (ws + 1048576);     // 34*64 u32   =    8704 B
  u32*   Wp1     = (u32*)  (ws + 1057792);     // 32*64 u32   =    8192 B
  u32*   Wp2     = (u32*)  (ws + 1065984);     // 32*128 u32  =   16384 B
  float* stats   = (float*)(ws + 1082368);     // 3*128*2 f32 =    3072 B
  float* affine  = (float*)(ws + 1085440);     // 3*128*2 f32 =    3072 B

  float* out_xyz  = (float*)d_out;                         // (16,3,1024) f32
  float* out_feat = (float*)d_out + (size_t)NB*3*NS;       // (16,128,1024) f32

  prep_kernel<<<1,256,0,stream>>>(W0,W1,W2,Wp0,Wp1,Wp2,stats);
  fps_kernel<<<NB,1024,0,stream>>>(xyz, out_xyz);
  ballq_kernel<<<NB*NS/4,256,0,stream>>>(xyz, out_xyz, gidx);

  mlp_pass<0><<<NSAMP/256,256,0,stream>>>(xyz,feat,out_xyz,gidx,Wp0,Wp1,Wp2,affine,stats,(u32*)out_feat);
  finalize_kernel<<<1,128,0,stream>>>(stats,     affine,     g0,b0, 64);
  mlp_pass<1><<<NSAMP/256,256,0,stream>>>(xyz,feat,out_xyz,gidx,Wp0,Wp1,Wp2,affine,stats,(u32*)out_feat);
  finalize_kernel<<<1,128,0,stream>>>(stats+256, affine+256, g1,b1, 64);
  mlp_pass<2><<<NSAMP/256,256,0,stream>>>(xyz,feat,out_xyz,gidx,Wp0,Wp1,Wp2,affine,stats,(u32*)out_feat);
  finalize_kernel<<<1,128,0,stream>>>(stats+512, affine+512, g2,b2, 128);
  apply_kernel<<<(NB*128*NS)/256,256,0,stream>>>(affine, out_feat);
}

// Round 9
// 2512.242 us; speedup vs baseline: 1.8495x; 1.8495x over previous
//
#include <hip/hip_runtime.h>

// PointNetSAModule on MI355X (gfx950).
// B=16, N=8192, CIN=64, S=1024, K=32, radius=0.2, MLP 67->64->64->128, eps=1e-5.
// Inputs/outputs float32 (proven R4). ws footprint = 1,087,488 B (< proven 1,088,512).
//
// R8 -> R9: MLP moved to MFMA (v_mfma_f32_16x16x32_f16). Three rounds of VGPR_Count
// evidence (32/44/72) prove the allocator spills any >32-float VALU array; MFMA
// accumulators are 4-float C/D fragments (AGPR-eligible) so nothing spills.
// Each wave owns 16 samples: gather -> LDS X panel (wave-local, no barriers),
// A=weight fragments prepacked in ws, B=activations from LDS, C/D in regs.
// fps unchanged from R8 (LDS coords version - left the top-5).

typedef unsigned short u16;
typedef unsigned int   u32;

#define NB    16
#define NPTS  8192
#define CINF  64
#define NS    1024
#define KK    32
#define NSAMP (NB*NS*KK)   // 524288

typedef _Float16 h2v   __attribute__((ext_vector_type(2)));
typedef _Float16 f16x8 __attribute__((ext_vector_type(8)));
typedef float    f32x4 __attribute__((ext_vector_type(4)));

static __device__ __forceinline__ h2v asH2(u32 x){ union{u32 u; h2v h;} v; v.u=x; return v.h; }
static __device__ __forceinline__ u32 asU32(h2v h){ union{u32 u; h2v h;} v; v.h=h; return v.u; }
static __device__ __forceinline__ u32 packh(float lo, float hi){
  union{ _Float16 h[2]; u32 u; } v;
  v.h[0]=(_Float16)lo; v.h[1]=(_Float16)hi; return v.u;
}
static __device__ __forceinline__ f32x4 zero4(){ f32x4 z; z[0]=0.f;z[1]=0.f;z[2]=0.f;z[3]=0.f; return z; }
static __device__ __forceinline__ f16x8 zero8h(){
  f16x8 z;
  #pragma unroll
  for (int i=0;i<8;i++) z[i]=(_Float16)0.f;
  return z;
}

// exact-order d^2, matching numpy f32: (dx*dx + dy*dy) + dz*dz, no FMA contraction
static __device__ __forceinline__ float d2_exact(float ax,float ay,float az,float bx,float by,float bz){
  float dx=__fsub_rn(ax,bx), dy=__fsub_rn(ay,by), dz=__fsub_rn(az,bz);
  return __fadd_rn(__fadd_rn(__fmul_rn(dx,dx),__fmul_rn(dy,dy)),__fmul_rn(dz,dz));
}

// ---------------------------------------------------------------- prep ----
// A-operand fragments in exact MFMA lane order: entry ((tc*2+kc)*64+lane)*4+d,
// lane m=lane&15 (channel row), q=lane>>4, k=kc*32+q*8+{2d,2d+1}.
// L1 fragments cover the 64 FEAT inputs only (W0 cols 3+k); xyz cols 0..2 are
// handled by an on-the-fly chunk in the kernel.
__global__ void prep_kernel(const float* __restrict__ W0, const float* __restrict__ W1,
                            const float* __restrict__ W2,
                            u32* __restrict__ Wf1, u32* __restrict__ Wf2, u32* __restrict__ Wf3,
                            float* __restrict__ stats)
{
  const int t = threadIdx.x;
  for (int i=t;i<768;i+=256) stats[i]=0.f;
  for (int i=t;i<2048;i+=256){           // L1: 4 tiles x 2 chunks
    int d=i&3, lane=(i>>2)&63, kc=(i>>8)&1, tc=i>>9;
    int row=tc*16+(lane&15), k0=kc*32+(lane>>4)*8+2*d;
    Wf1[i]=packh(W0[row*67+3+k0], W0[row*67+4+k0]);
  }
  for (int i=t;i<2048;i+=256){           // L2: 4 tiles x 2 chunks
    int d=i&3, lane=(i>>2)&63, kc=(i>>8)&1, tc=i>>9;
    int row=tc*16+(lane&15), k0=kc*32+(lane>>4)*8+2*d;
    Wf2[i]=packh(W1[row*64+k0], W1[row*64+k0+1]);
  }
  for (int i=t;i<4096;i+=256){           // L3: 8 tiles x 2 chunks
    int d=i&3, lane=(i>>2)&63, kc=(i>>8)&1, tc=i>>9;
    int row=tc*16+(lane&15), k0=kc*32+(lane>>4)*8+2*d;
    Wf3[i]=packh(W2[row*64+k0], W2[row*64+k0+1]);
  }
}

// ----------------------------------------------------------------- FPS ----
// one block per batch; 1024 threads, 8 consecutive points/thread in LDS
// (28-f32 regions, 2-way banks = free). dist[8] loop-carried in regs.
__global__ __launch_bounds__(1024,1) void fps_kernel(const float* __restrict__ xyz,
    float* __restrict__ out_xyz)
{
  __shared__ float sc[1024*28];            // 114,688 B
  __shared__ float s_v[2][16];
  __shared__ int   s_i[2][16];
  const int b = blockIdx.x, t = threadIdx.x;
  const float* xb = xyz + (size_t)b*3*NPTS;
  const int tb = t*28;
  #pragma unroll
  for (int i=0;i<8;i++){
    const int idx = 8*t + i;
    sc[tb+i]    = xb[idx];
    sc[tb+8+i]  = xb[NPTS+idx];
    sc[tb+16+i] = xb[2*NPTS+idx];
  }
  float d[8];
  #pragma unroll
  for (int i=0;i<8;i++) d[i]=__builtin_inff();
  __syncthreads();
  float cx = xb[0], cy = xb[NPTS], cz = xb[2*NPTS];   // initial center = point 0
  const int lane = t & 63, wv = t >> 6, l16 = lane & 15;
  for (int step=0; step<NS; step++){
    if (t==0){
      out_xyz[(size_t)(b*3+0)*NS+step]=cx;
      out_xyz[(size_t)(b*3+1)*NS+step]=cy;
      out_xyz[(size_t)(b*3+2)*NS+step]=cz;
    }
    if (step==NS-1) break;
    float4 X0 = *(const float4*)&sc[tb];
    float4 X1 = *(const float4*)&sc[tb+4];
    float4 Y0 = *(const float4*)&sc[tb+8];
    float4 Y1 = *(const float4*)&sc[tb+12];
    float4 Z0 = *(const float4*)&sc[tb+16];
    float4 Z1 = *(const float4*)&sc[tb+20];
    float bv=-1.f; int bi=0;
#define UPD(i, PX, PY, PZ) { \
    float d2 = d2_exact(PX,PY,PZ, cx,cy,cz); \
    float nd = fminf(d[i], d2); d[i]=nd; \
    if (nd>bv){ bv=nd; bi=8*t+i; } }
    UPD(0, X0.x, Y0.x, Z0.x)  UPD(1, X0.y, Y0.y, Z0.y)
    UPD(2, X0.z, Y0.z, Z0.z)  UPD(3, X0.w, Y0.w, Z0.w)
    UPD(4, X1.x, Y1.x, Z1.x)  UPD(5, X1.y, Y1.y, Z1.y)
    UPD(6, X1.z, Y1.z, Z1.z)  UPD(7, X1.w, Y1.w, Z1.w)
#undef UPD
    #pragma unroll
    for (int off=1; off<64; off<<=1){    // wave argmax, smallest-index tie-break
      float ov=__shfl_xor(bv,off); int oi=__shfl_xor(bi,off);
      bool take = (ov>bv) || (ov==bv && oi<bi);
      bv=take?ov:bv; bi=take?oi:bi;
    }
    const int p = step&1;                // double-buffered -> single barrier/step
    if (lane==0){ s_v[p][wv]=bv; s_i[p][wv]=bi; }
    __syncthreads();
    bv = s_v[p][l16]; bi = s_i[p][l16];
    #pragma unroll
    for (int off=1; off<16; off<<=1){
      float ov=__shfl_xor(bv,off); int oi=__shfl_xor(bi,off);
      bool take = (ov>bv) || (ov==bv && oi<bi);
      bv=take?ov:bv; bi=take?oi:bi;
    }
    const int w = bi, wt = w>>3, wi = w&7, wb = wt*28;
    cx = sc[wb+wi]; cy = sc[wb+8+wi]; cz = sc[wb+16+wi];
  }
}

// ---------------------------------------------------------- ball query ----
__global__ __launch_bounds__(256) void ballq_kernel(const float* __restrict__ xyz,
    const float* __restrict__ out_xyz, u16* __restrict__ gidx)
{
  const int gid = blockIdx.x*4 + (threadIdx.x>>6);
  const int lane = threadIdx.x & 63;
  const int b = gid >> 10, s = gid & (NS-1);
  const float* xb = xyz + (size_t)b*3*NPTS;
  const float cx = out_xyz[(size_t)(b*3+0)*NS+s];
  const float cy = out_xyz[(size_t)(b*3+1)*NS+s];
  const float cz = out_xyz[(size_t)(b*3+2)*NS+s];
  u16* out = gidx + (size_t)gid*KK;
  int cnt=0, first=-1;
  for (int base=0; base<NPTS; base+=64){
    const int pidx = base + lane;
    float d2 = d2_exact(cx,cy,cz, xb[pidx], xb[NPTS+pidx], xb[2*NPTS+pidx]);
    bool within = d2 < 0.04f;
    unsigned long long m = __ballot(within);
    if (m){
      if (first<0) first = base + (__ffsll(m)-1);
      int pos = cnt + (int)__popcll(m & ((1ull<<lane)-1ull));
      if (within && pos<KK) out[pos]=(u16)pidx;
      cnt += (int)__popcll(m);
      if (cnt>=KK) break;
    }
  }
  if (first<0) first=0;
  for (int posi = cnt + lane; posi < KK; posi += 64) out[posi]=(u16)first;
}

// --------------------------------------------------------------- MLP -----
// STAGE 0: stats(y1) | 1: stats(y2) | 2: stats(y3) + (max,min) over K -> out.
// Block = 256 thr = 4 waves; 4 chunks x 64 samples; wave owns 16 samples.
// X panel: [sample][48 dwords]: [0..31] 64xf16 feats (later: activations),
// [32..33] dxyz f16, [34..47] zeros. Wave-local -> no barriers in the pipeline.
#define MFMA16(A,B,C) __builtin_amdgcn_mfma_f32_16x16x32_f16(A,B,C,0,0,0)

template<int STAGE>
__global__ __launch_bounds__(256,2) void mlp_pass(
    const float* __restrict__ xyz, const float* __restrict__ feat,
    const float* __restrict__ out_xyz, const u16* __restrict__ gidx,
    const u32* __restrict__ Wf1, const u32* __restrict__ Wf2, const u32* __restrict__ Wf3,
    const float* __restrict__ W0raw,
    const float* __restrict__ affine, float* __restrict__ stats, u32* __restrict__ outMM)
{
  constexpr int TCO = (STAGE==2)?128:64;
  __shared__ alignas(16) u32 Xs[64*48];          // 12 KB
  __shared__ float bins[2*TCO];
  __shared__ u32 mm[(STAGE==2)? 2*4*128 : 4];    // double-buffered cross-wave panel

  const int t = threadIdx.x;
  const int lane = t&63, w = t>>6, n = lane&15, q = lane>>4;
  const int j = t>>2, q4 = t&3;                  // gather role: sample j, quarter q4
  const int colbase = (w*16+n)*48;
  if (t < 2*TCO) bins[t]=0.f;
  __syncthreads();                               // bins zero visible to all

  #pragma unroll 1
  for (int ch=0; ch<4; ch++){
    const int ss = blockIdx.x*256 + ch*64 + j;   // flat (b,s,k)
    const int b = ss >> 15;
    const int s = (ss >> 5) & (NS-1);
    const int g = ((int)gidx[ss]) & (NPTS-1);
    // ---- gather: 4 threads per sample, 16 feats each; q4==3 adds dxyz ----
    {
      const float* fb = feat + (size_t)b*CINF*NPTS + g;
      u32* Xrow = &Xs[j*48];
      #pragma unroll
      for (int m2=0;m2<8;m2++){
        float a0 = fb[(size_t)(16*q4+2*m2)*NPTS];
        float a1 = fb[(size_t)(16*q4+2*m2+1)*NPTS];
        Xrow[8*q4+m2] = packh(a0,a1);
      }
      if (q4==3){
        const float* xb = xyz + (size_t)b*3*NPTS;
        float dx=__fsub_rn(xb[g],        out_xyz[(size_t)(b*3+0)*NS+s]);
        float dy=__fsub_rn(xb[NPTS+g],   out_xyz[(size_t)(b*3+1)*NS+s]);
        float dz=__fsub_rn(xb[2*NPTS+g], out_xyz[(size_t)(b*3+2)*NS+s]);
        Xrow[32]=packh(dx,dy); Xrow[33]=packh(dz,0.f);
      }
      #pragma unroll
      for (int i=34+q4;i<48;i+=4) Xrow[i]=0;
    }
    // ---- layer 1: Y1(64ch x 16smp) = W0 * X ----
    f32x4 acc[4];
    #pragma unroll
    for (int tc=0;tc<4;tc++) acc[tc]=zero4();
    #pragma unroll
    for (int kc=0;kc<2;kc++){
      f16x8 Bf = *(const f16x8*)&Xs[colbase + kc*16 + q*4];
      #pragma unroll
      for (int tc=0;tc<4;tc++){
        f16x8 Af = *(const f16x8*)&Wf1[((tc*2+kc)*64+lane)*4];
        acc[tc] = MFMA16(Af,Bf,acc[tc]);
      }
    }
    {  // xyz chunk: only q==0/j<3 of A nonzero (W0 cols 0..2), B dwords 32..47
      f16x8 Bf = *(const f16x8*)&Xs[colbase + 32 + q*4];
      #pragma unroll
      for (int tc=0;tc<4;tc++){
        f16x8 Af = zero8h();
        if (q==0){
          const int row = tc*16+n;
          Af[0]=(_Float16)W0raw[row*67+0];
          Af[1]=(_Float16)W0raw[row*67+1];
          Af[2]=(_Float16)W0raw[row*67+2];
        }
        acc[tc] = MFMA16(Af,Bf,acc[tc]);
      }
    }

    if constexpr (STAGE==0){
      #pragma unroll
      for (int tc=0;tc<4;tc++){
        #pragma unroll
        for (int r=0;r<4;r++){
          float s1=acc[tc][r], s2=__fmul_rn(s1,s1);
          #pragma unroll
          for (int off=1;off<16;off<<=1){ s1+=__shfl_xor(s1,off); s2+=__shfl_xor(s2,off); }
          if (n==0){ const int c=tc*16+q*4+r;
            atomicAdd(&bins[c], s1); atomicAdd(&bins[TCO+c], s2); }
        }
      }
    } else {
      // affine L1 + relu -> f16 -> X panel (C/D rows are contiguous per reg pair)
      #pragma unroll
      for (int tc=0;tc<4;tc++){
        const f32x4 sc4 = *(const f32x4*)&affine[tc*16+q*4];
        const f32x4 sh4 = *(const f32x4*)&affine[128+tc*16+q*4];
        Xs[colbase + tc*8+q*2]   = packh(fmaxf(fmaf(acc[tc][0],sc4[0],sh4[0]),0.f),
                                         fmaxf(fmaf(acc[tc][1],sc4[1],sh4[1]),0.f));
        Xs[colbase + tc*8+q*2+1] = packh(fmaxf(fmaf(acc[tc][2],sc4[2],sh4[2]),0.f),
                                         fmaxf(fmaf(acc[tc][3],sc4[3],sh4[3]),0.f));
      }
      // ---- layer 2 ----
      f32x4 acc2[4];
      #pragma unroll
      for (int tc=0;tc<4;tc++) acc2[tc]=zero4();
      #pragma unroll
      for (int kc=0;kc<2;kc++){
        f16x8 Bf = *(const f16x8*)&Xs[colbase + kc*16 + q*4];
        #pragma unroll
        for (int tc=0;tc<4;tc++){
          f16x8 Af = *(const f16x8*)&Wf2[((tc*2+kc)*64+lane)*4];
          acc2[tc] = MFMA16(Af,Bf,acc2[tc]);
        }
      }
      if constexpr (STAGE==1){
        #pragma unroll
        for (int tc=0;tc<4;tc++){
          #pragma unroll
          for (int r=0;r<4;r++){
            float s1=acc2[tc][r], s2=__fmul_rn(s1,s1);
            #pragma unroll
            for (int off=1;off<16;off<<=1){ s1+=__shfl_xor(s1,off); s2+=__shfl_xor(s2,off); }
            if (n==0){ const int c=tc*16+q*4+r;
              atomicAdd(&bins[c], s1); atomicAdd(&bins[TCO+c], s2); }
          }
        }
      } else {
        #pragma unroll
        for (int tc=0;tc<4;tc++){
          const f32x4 sc4 = *(const f32x4*)&affine[256+tc*16+q*4];
          const f32x4 sh4 = *(const f32x4*)&affine[256+128+tc*16+q*4];
          Xs[colbase + tc*8+q*2]   = packh(fmaxf(fmaf(acc2[tc][0],sc4[0],sh4[0]),0.f),
                                           fmaxf(fmaf(acc2[tc][1],sc4[1],sh4[1]),0.f));
          Xs[colbase + tc*8+q*2+1] = packh(fmaxf(fmaf(acc2[tc][2],sc4[2],sh4[2]),0.f),
                                           fmaxf(fmaf(acc2[tc][3],sc4[3],sh4[3]),0.f));
        }
        // ---- layer 3 (128 ch) ----
        f32x4 acc3[8];
        #pragma unroll
        for (int tc=0;tc<8;tc++) acc3[tc]=zero4();
        #pragma unroll
        for (int kc=0;kc<2;kc++){
          f16x8 Bf = *(const f16x8*)&Xs[colbase + kc*16 + q*4];
          #pragma unroll
          for (int tc=0;tc<8;tc++){
            f16x8 Af = *(const f16x8*)&Wf3[((tc*2+kc)*64+lane)*4];
            acc3[tc] = MFMA16(Af,Bf,acc3[tc]);
          }
        }
        u32* mmb = &mm[(ch&1)*512];
        #pragma unroll
        for (int tc=0;tc<8;tc++){
          #pragma unroll
          for (int r=0;r<4;r++){
            float y=acc3[tc][r];
            float s1=y, s2=__fmul_rn(y,y);
            u32 pm = packh(y, -y);                       // (max, -min) carrier
            #pragma unroll
            for (int off=1;off<16;off<<=1){
              s1+=__shfl_xor(s1,off); s2+=__shfl_xor(s2,off);
              u32 o = (u32)__shfl_xor((int)pm,off);
              pm = asU32(__builtin_elementwise_max(asH2(pm), asH2(o)));
            }
            if (n==0){ const int c=tc*16+q*4+r;
              atomicAdd(&bins[c], s1); atomicAdd(&bins[128+c], s2);
              mmb[w*128+c]=pm; }
          }
        }
        __syncthreads();                                 // mm panel ready
        {
          const int c = t&127, gg = t>>7;                // 2 groups of 32 per chunk
          u32 a = mmb[(2*gg)*128+c], b2 = mmb[(2*gg+1)*128+c];
          h2v hm = __builtin_elementwise_max(asH2(a), asH2(b2));
          const int s0 = ((blockIdx.x*8 + ch*2) & (NS-1)) + gg;
          outMM[((size_t)b*128+c)*NS + s0] = packh((float)hm[0], -(float)hm[1]);
        }
      }
    }
  }

  __syncthreads();
  if (t < TCO){
    atomicAdd(&stats[STAGE*256 + 2*t],   bins[t]);
    atomicAdd(&stats[STAGE*256 + 2*t+1], bins[TCO+t]);
  }
}

// ----------------------------------------------------------- finalize ----
// affine SoA per layer: af[c]=scale, af[128+c]=shift
__global__ void finalize_kernel(const float* __restrict__ st, float* __restrict__ af,
                                const float* __restrict__ gamma, const float* __restrict__ beta, int C)
{
  int c = threadIdx.x;
  if (c < C){
    float mean = st[2*c] * (1.f/524288.f);
    float var  = fmaxf(st[2*c+1] * (1.f/524288.f) - mean*mean, 0.f);
    float rstd = 1.f / sqrtf(var + 1e-5f);
    float sc = rstd * gamma[c];
    af[c]     = sc;
    af[128+c] = beta[c] - mean*sc;
  }
}

// -------------------------------------------------------------- apply ----
// out_feat[i] holds packed f16 (max_k y3, min_k y3); finish BN+relu.
__global__ void apply_kernel(const float* __restrict__ affine, float* __restrict__ outF)
{
  const int i = blockIdx.x*256 + threadIdx.x;      // 16*128*1024 elements
  const int c = (i >> 10) & 127;
  u32 v = ((const u32*)outF)[i];
  h2v h = asH2(v);
  float sc = affine[512+c], sh = affine[512+128+c];
  float cand = (sc > 0.f) ? (float)h[0] : (float)h[1];
  outF[i] = fmaxf(fmaf(cand, sc, sh), 0.f);
}

// ------------------------------------------------------------- launch ----
extern "C" void kernel_launch(void* const* d_in, const int* in_sizes, int n_in,
                              void* d_out, int out_size, void* d_ws, size_t ws_size,
                              hipStream_t stream)
{
  (void)in_sizes; (void)n_in; (void)out_size; (void)ws_size;
  const float* xyz  = (const float*)d_in[0];
  const float* feat = (const float*)d_in[1];
  const float* W0 = (const float*)d_in[2];
  const float* g0 = (const float*)d_in[3];
  const float* b0 = (const float*)d_in[4];
  const float* W1 = (const float*)d_in[5];
  const float* g1 = (const float*)d_in[6];
  const float* b1 = (const float*)d_in[7];
  const float* W2 = (const float*)d_in[8];
  const float* g2 = (const float*)d_in[9];
  const float* b2 = (const float*)d_in[10];

  char* ws = (char*)d_ws;                      // 1,087,488 B total (< proven 1,088,512)
  u16*   gidx    = (u16*)  (ws + 0);           // 524288 u16  = 1048576 B
  u32*   Wf1     = (u32*)  (ws + 1048576);     // 2048 u32    =    8192 B
  u32*   Wf2     = (u32*)  (ws + 1056768);     // 2048 u32    =    8192 B
  u32*   Wf3     = (u32*)  (ws + 1064960);     // 4096 u32    =   16384 B
  float* stats   = (float*)(ws + 1081344);     // 768 f32     =    3072 B
  float* affine  = (float*)(ws + 1084416);     // 768 f32     =    3072 B

  float* out_xyz  = (float*)d_out;                         // (16,3,1024) f32
  float* out_feat = (float*)d_out + (size_t)NB*3*NS;       // (16,128,1024) f32

  prep_kernel<<<1,256,0,stream>>>(W0,W1,W2,Wf1,Wf2,Wf3,stats);
  fps_kernel<<<NB,1024,0,stream>>>(xyz, out_xyz);
  ballq_kernel<<<NB*NS/4,256,0,stream>>>(xyz, out_xyz, gidx);

  mlp_pass<0><<<NSAMP/256,256,0,stream>>>(xyz,feat,out_xyz,gidx,Wf1,Wf2,Wf3,W0,affine,stats,(u32*)out_feat);
  finalize_kernel<<<1,128,0,stream>>>(stats,     affine,     g0,b0, 64);
  mlp_pass<1><<<NSAMP/256,256,0,stream>>>(xyz,feat,out_xyz,gidx,Wf1,Wf2,Wf3,W0,affine,stats,(u32*)out_feat);
  finalize_kernel<<<1,128,0,stream>>>(stats+256, affine+256, g1,b1, 64);
  mlp_pass<2><<<NSAMP/256,256,0,stream>>>(xyz,feat,out_xyz,gidx,Wf1,Wf2,Wf3,W0,affine,stats,(u32*)out_feat);
  finalize_kernel<<<1,128,0,stream>>>(stats+512, affine+512, g2,b2, 128);
  apply_kernel<<<(NB*128*NS)/256,256,0,stream>>>(affine, out_feat);
}

// Round 10
// 1992.816 us; speedup vs baseline: 2.3315x; 1.2606x over previous
//
#include <hip/hip_runtime.h>

// PointNetSAModule on MI355X (gfx950).
// B=16, N=8192, CIN=64, S=1024, K=32, radius=0.2, MLP 67->64->64->128, eps=1e-5.
// Inputs/outputs float32 (proven R4). ws footprint = 1,087,488 B (< proven 1,088,512).
//
// R9 -> R10: fps argmax reduction moved from __shfl_xor (ds_bpermute -> saturated
// LDS pipe, ~1900 cy/step) to DPP on the VALU pipe, with (dist,idx) packed as a
// u64 lexicographic key (dist_bits<<32 | 8191-idx; non-negative floats compare
// as uints; 8191-idx = smallest-index tie-break). MLP (MFMA) unchanged from R9.

typedef unsigned short u16;
typedef unsigned int   u32;
typedef unsigned long long u64;

#define NB    16
#define NPTS  8192
#define CINF  64
#define NS    1024
#define KK    32
#define NSAMP (NB*NS*KK)   // 524288

typedef _Float16 h2v   __attribute__((ext_vector_type(2)));
typedef _Float16 f16x8 __attribute__((ext_vector_type(8)));
typedef float    f32x4 __attribute__((ext_vector_type(4)));

static __device__ __forceinline__ h2v asH2(u32 x){ union{u32 u; h2v h;} v; v.u=x; return v.h; }
static __device__ __forceinline__ u32 asU32(h2v h){ union{u32 u; h2v h;} v; v.h=h; return v.u; }
static __device__ __forceinline__ u32 packh(float lo, float hi){
  union{ _Float16 h[2]; u32 u; } v;
  v.h[0]=(_Float16)lo; v.h[1]=(_Float16)hi; return v.u;
}
static __device__ __forceinline__ f32x4 zero4(){ f32x4 z; z[0]=0.f;z[1]=0.f;z[2]=0.f;z[3]=0.f; return z; }
static __device__ __forceinline__ f16x8 zero8h(){
  f16x8 z;
  #pragma unroll
  for (int i=0;i<8;i++) z[i]=(_Float16)0.f;
  return z;
}

// exact-order d^2, matching numpy f32: (dx*dx + dy*dy) + dz*dz, no FMA contraction
static __device__ __forceinline__ float d2_exact(float ax,float ay,float az,float bx,float by,float bz){
  float dx=__fsub_rn(ax,bx), dy=__fsub_rn(ay,by), dz=__fsub_rn(az,bz);
  return __fadd_rn(__fadd_rn(__fmul_rn(dx,dx),__fmul_rn(dy,dy)),__fmul_rn(dz,dz));
}

// one DPP combine level for the (kv,ki) lexicographic max
#if __has_builtin(__builtin_amdgcn_update_dpp)
#define HAVE_DPP 1
template<int CTRL, int RMASK>
static __device__ __forceinline__ void dppmax(u32 &kv, u32 &ki){
  u32 okv = (u32)__builtin_amdgcn_update_dpp((int)kv, (int)kv, CTRL, RMASK, 0xf, false);
  u32 oki = (u32)__builtin_amdgcn_update_dpp((int)ki, (int)ki, CTRL, RMASK, 0xf, false);
  u64 A = (((u64)okv)<<32) | oki;
  u64 B = (((u64)kv )<<32) | ki;
  if (A > B){ kv = okv; ki = oki; }
}
#else
#define HAVE_DPP 0
#endif

// ---------------------------------------------------------------- prep ----
// A-operand fragments in exact MFMA lane order: entry ((tc*2+kc)*64+lane)*4+d,
// lane m=lane&15 (channel row), q=lane>>4, k=kc*32+q*8+{2d,2d+1}.
__global__ void prep_kernel(const float* __restrict__ W0, const float* __restrict__ W1,
                            const float* __restrict__ W2,
                            u32* __restrict__ Wf1, u32* __restrict__ Wf2, u32* __restrict__ Wf3,
                            float* __restrict__ stats)
{
  const int t = threadIdx.x;
  for (int i=t;i<768;i+=256) stats[i]=0.f;
  for (int i=t;i<2048;i+=256){           // L1: 4 tiles x 2 chunks (feat cols only)
    int d=i&3, lane=(i>>2)&63, kc=(i>>8)&1, tc=i>>9;
    int row=tc*16+(lane&15), k0=kc*32+(lane>>4)*8+2*d;
    Wf1[i]=packh(W0[row*67+3+k0], W0[row*67+4+k0]);
  }
  for (int i=t;i<2048;i+=256){           // L2
    int d=i&3, lane=(i>>2)&63, kc=(i>>8)&1, tc=i>>9;
    int row=tc*16+(lane&15), k0=kc*32+(lane>>4)*8+2*d;
    Wf2[i]=packh(W1[row*64+k0], W1[row*64+k0+1]);
  }
  for (int i=t;i<4096;i+=256){           // L3
    int d=i&3, lane=(i>>2)&63, kc=(i>>8)&1, tc=i>>9;
    int row=tc*16+(lane&15), k0=kc*32+(lane>>4)*8+2*d;
    Wf3[i]=packh(W2[row*64+k0], W2[row*64+k0+1]);
  }
}

// ----------------------------------------------------------------- FPS ----
// one block per batch; 1024 threads, 8 consecutive points/thread in LDS
// (28-f32 regions, 2-way banks = free). dist[8] loop-carried in regs.
// Argmax: u64 key (dist_bits<<32 | 8191-idx), 6 DPP levels (VALU pipe) ->
// lane 63 -> readlane -> 16 LDS slots -> 4 DPP levels -> scalar winner.
__global__ __launch_bounds__(1024,1) void fps_kernel(const float* __restrict__ xyz,
    float* __restrict__ out_xyz)
{
  __shared__ float sc[1024*28];            // 114,688 B
  __shared__ u32 s_kv[2][16], s_ki[2][16];
  const int b = blockIdx.x, t = threadIdx.x;
  const float* xb = xyz + (size_t)b*3*NPTS;
  const int tb = t*28;
  #pragma unroll
  for (int i=0;i<8;i++){
    const int idx = 8*t + i;
    sc[tb+i]    = xb[idx];
    sc[tb+8+i]  = xb[NPTS+idx];
    sc[tb+16+i] = xb[2*NPTS+idx];
  }
  float d[8];
  #pragma unroll
  for (int i=0;i<8;i++) d[i]=__builtin_inff();
  __syncthreads();
  float cx = xb[0], cy = xb[NPTS], cz = xb[2*NPTS];   // initial center = point 0
  const int lane = t & 63, wv = t >> 6, l16 = lane & 15;
  const u32 kibase = (u32)(NPTS-1 - 8*t);
  for (int step=0; step<NS; step++){
    if (t==0){
      out_xyz[(size_t)(b*3+0)*NS+step]=cx;
      out_xyz[(size_t)(b*3+1)*NS+step]=cy;
      out_xyz[(size_t)(b*3+2)*NS+step]=cz;
    }
    if (step==NS-1) break;
    float4 X0 = *(const float4*)&sc[tb];
    float4 X1 = *(const float4*)&sc[tb+4];
    float4 Y0 = *(const float4*)&sc[tb+8];
    float4 Y1 = *(const float4*)&sc[tb+12];
    float4 Z0 = *(const float4*)&sc[tb+16];
    float4 Z1 = *(const float4*)&sc[tb+20];
    u32 bkv, bki;
    { float d2 = d2_exact(X0.x,Y0.x,Z0.x, cx,cy,cz);
      float nd = fminf(d[0], d2); d[0]=nd;
      bkv = __float_as_uint(nd); bki = kibase; }
#define UPD(i, PX, PY, PZ) { \
    float d2 = d2_exact(PX,PY,PZ, cx,cy,cz); \
    float nd = fminf(d[i], d2); d[i]=nd; \
    u32 kv = __float_as_uint(nd), ki = kibase - i; \
    u64 A = (((u64)kv)<<32)|ki, Bq = (((u64)bkv)<<32)|bki; \
    if (A > Bq){ bkv=kv; bki=ki; } }
    UPD(1, X0.y, Y0.y, Z0.y)  UPD(2, X0.z, Y0.z, Z0.z)  UPD(3, X0.w, Y0.w, Z0.w)
    UPD(4, X1.x, Y1.x, Z1.x)  UPD(5, X1.y, Y1.y, Z1.y)
    UPD(6, X1.z, Y1.z, Z1.z)  UPD(7, X1.w, Y1.w, Z1.w)
#undef UPD

#if HAVE_DPP
    dppmax<0xB1,0xf>(bkv,bki);           // quad_perm xor1
    dppmax<0x4E,0xf>(bkv,bki);           // quad_perm xor2
    dppmax<0x141,0xf>(bkv,bki);          // row_half_mirror (combine quads)
    dppmax<0x140,0xf>(bkv,bki);          // row_mirror (combine 8-groups)
    dppmax<0x142,0xa>(bkv,bki);          // row_bcast15 (rows 1,3)
    dppmax<0x143,0xc>(bkv,bki);          // row_bcast31 (rows 2,3) -> lane 63
    u32 wkv = (u32)__builtin_amdgcn_readlane((int)bkv, 63);
    u32 wki = (u32)__builtin_amdgcn_readlane((int)bki, 63);
#else
    #pragma unroll
    for (int off=1; off<64; off<<=1){
      u32 okv=(u32)__shfl_xor((int)bkv,off), oki=(u32)__shfl_xor((int)bki,off);
      u64 A=(((u64)okv)<<32)|oki, Bq=(((u64)bkv)<<32)|bki;
      if (A>Bq){ bkv=okv; bki=oki; }
    }
    u32 wkv=bkv, wki=bki;
#endif
    const int p = step&1;                // double-buffered -> single barrier/step
    if (lane==0){ s_kv[p][wv]=wkv; s_ki[p][wv]=wki; }
    __syncthreads();
    u32 kv2 = s_kv[p][l16], ki2 = s_ki[p][l16];
#if HAVE_DPP
    dppmax<0xB1,0xf>(kv2,ki2);
    dppmax<0x4E,0xf>(kv2,ki2);
    dppmax<0x141,0xf>(kv2,ki2);
    dppmax<0x140,0xf>(kv2,ki2);          // all 16 lanes hold block winner
    const int widx = (NPTS-1) - (int)__builtin_amdgcn_readlane((int)ki2, 0);
#else
    #pragma unroll
    for (int off=1; off<16; off<<=1){
      u32 okv=(u32)__shfl_xor((int)kv2,off), oki=(u32)__shfl_xor((int)ki2,off);
      u64 A=(((u64)okv)<<32)|oki, Bq=(((u64)kv2)<<32)|ki2;
      if (A>Bq){ kv2=okv; ki2=oki; }
    }
    const int widx = (NPTS-1) - (int)ki2;
#endif
    const int wb2 = (widx>>3)*28, wi = widx&7;
    cx = sc[wb2+wi]; cy = sc[wb2+8+wi]; cz = sc[wb2+16+wi];
  }
}

// ---------------------------------------------------------- ball query ----
__global__ __launch_bounds__(256) void ballq_kernel(const float* __restrict__ xyz,
    const float* __restrict__ out_xyz, u16* __restrict__ gidx)
{
  const int gid = blockIdx.x*4 + (threadIdx.x>>6);
  const int lane = threadIdx.x & 63;
  const int b = gid >> 10, s = gid & (NS-1);
  const float* xb = xyz + (size_t)b*3*NPTS;
  const float cx = out_xyz[(size_t)(b*3+0)*NS+s];
  const float cy = out_xyz[(size_t)(b*3+1)*NS+s];
  const float cz = out_xyz[(size_t)(b*3+2)*NS+s];
  u16* out = gidx + (size_t)gid*KK;
  int cnt=0, first=-1;
  for (int base=0; base<NPTS; base+=64){
    const int pidx = base + lane;
    float d2 = d2_exact(cx,cy,cz, xb[pidx], xb[NPTS+pidx], xb[2*NPTS+pidx]);
    bool within = d2 < 0.04f;
    unsigned long long m = __ballot(within);
    if (m){
      if (first<0) first = base + (__ffsll(m)-1);
      int pos = cnt + (int)__popcll(m & ((1ull<<lane)-1ull));
      if (within && pos<KK) out[pos]=(u16)pidx;
      cnt += (int)__popcll(m);
      if (cnt>=KK) break;
    }
  }
  if (first<0) first=0;
  for (int posi = cnt + lane; posi < KK; posi += 64) out[posi]=(u16)first;
}

// --------------------------------------------------------------- MLP -----
// STAGE 0: stats(y1) | 1: stats(y2) | 2: stats(y3) + (max,min) over K -> out.
// Block = 256 thr = 4 waves; 4 chunks x 64 samples; wave owns 16 samples.
#define MFMA16(A,B,C) __builtin_amdgcn_mfma_f32_16x16x32_f16(A,B,C,0,0,0)

template<int STAGE>
__global__ __launch_bounds__(256,2) void mlp_pass(
    const float* __restrict__ xyz, const float* __restrict__ feat,
    const float* __restrict__ out_xyz, const u16* __restrict__ gidx,
    const u32* __restrict__ Wf1, const u32* __restrict__ Wf2, const u32* __restrict__ Wf3,
    const float* __restrict__ W0raw,
    const float* __restrict__ affine, float* __restrict__ stats, u32* __restrict__ outMM)
{
  constexpr int TCO = (STAGE==2)?128:64;
  __shared__ alignas(16) u32 Xs[64*48];          // 12 KB
  __shared__ float bins[2*TCO];
  __shared__ u32 mm[(STAGE==2)? 2*4*128 : 4];    // double-buffered cross-wave panel

  const int t = threadIdx.x;
  const int lane = t&63, w = t>>6, n = lane&15, q = lane>>4;
  const int j = t>>2, q4 = t&3;                  // gather role: sample j, quarter q4
  const int colbase = (w*16+n)*48;
  if (t < 2*TCO) bins[t]=0.f;
  __syncthreads();                               // bins zero visible to all

  #pragma unroll 1
  for (int ch=0; ch<4; ch++){
    const int ss = blockIdx.x*256 + ch*64 + j;   // flat (b,s,k)
    const int b = ss >> 15;
    const int s = (ss >> 5) & (NS-1);
    const int g = ((int)gidx[ss]) & (NPTS-1);
    // ---- gather: 4 threads per sample, 16 feats each; q4==3 adds dxyz ----
    {
      const float* fb = feat + (size_t)b*CINF*NPTS + g;
      u32* Xrow = &Xs[j*48];
      #pragma unroll
      for (int m2=0;m2<8;m2++){
        float a0 = fb[(size_t)(16*q4+2*m2)*NPTS];
        float a1 = fb[(size_t)(16*q4+2*m2+1)*NPTS];
        Xrow[8*q4+m2] = packh(a0,a1);
      }
      if (q4==3){
        const float* xb = xyz + (size_t)b*3*NPTS;
        float dx=__fsub_rn(xb[g],        out_xyz[(size_t)(b*3+0)*NS+s]);
        float dy=__fsub_rn(xb[NPTS+g],   out_xyz[(size_t)(b*3+1)*NS+s]);
        float dz=__fsub_rn(xb[2*NPTS+g], out_xyz[(size_t)(b*3+2)*NS+s]);
        Xrow[32]=packh(dx,dy); Xrow[33]=packh(dz,0.f);
      }
      #pragma unroll
      for (int i=34+q4;i<48;i+=4) Xrow[i]=0;
    }
    // ---- layer 1: Y1(64ch x 16smp) = W0 * X ----
    f32x4 acc[4];
    #pragma unroll
    for (int tc=0;tc<4;tc++) acc[tc]=zero4();
    #pragma unroll
    for (int kc=0;kc<2;kc++){
      f16x8 Bf = *(const f16x8*)&Xs[colbase + kc*16 + q*4];
      #pragma unroll
      for (int tc=0;tc<4;tc++){
        f16x8 Af = *(const f16x8*)&Wf1[((tc*2+kc)*64+lane)*4];
        acc[tc] = MFMA16(Af,Bf,acc[tc]);
      }
    }
    {  // xyz chunk: only q==0 of A nonzero (W0 cols 0..2), B dwords 32..47
      f16x8 Bf = *(const f16x8*)&Xs[colbase + 32 + q*4];
      #pragma unroll
      for (int tc=0;tc<4;tc++){
        f16x8 Af = zero8h();
        if (q==0){
          const int row = tc*16+n;
          Af[0]=(_Float16)W0raw[row*67+0];
          Af[1]=(_Float16)W0raw[row*67+1];
          Af[2]=(_Float16)W0raw[row*67+2];
        }
        acc[tc] = MFMA16(Af,Bf,acc[tc]);
      }
    }

    if constexpr (STAGE==0){
      #pragma unroll
      for (int tc=0;tc<4;tc++){
        #pragma unroll
        for (int r=0;r<4;r++){
          float s1=acc[tc][r], s2=__fmul_rn(s1,s1);
          #pragma unroll
          for (int off=1;off<16;off<<=1){ s1+=__shfl_xor(s1,off); s2+=__shfl_xor(s2,off); }
          if (n==0){ const int c=tc*16+q*4+r;
            atomicAdd(&bins[c], s1); atomicAdd(&bins[TCO+c], s2); }
        }
      }
    } else {
      // affine L1 + relu -> f16 -> X panel
      #pragma unroll
      for (int tc=0;tc<4;tc++){
        const f32x4 sc4 = *(const f32x4*)&affine[tc*16+q*4];
        const f32x4 sh4 = *(const f32x4*)&affine[128+tc*16+q*4];
        Xs[colbase + tc*8+q*2]   = packh(fmaxf(fmaf(acc[tc][0],sc4[0],sh4[0]),0.f),
                                         fmaxf(fmaf(acc[tc][1],sc4[1],sh4[1]),0.f));
        Xs[colbase + tc*8+q*2+1] = packh(fmaxf(fmaf(acc[tc][2],sc4[2],sh4[2]),0.f),
                                         fmaxf(fmaf(acc[tc][3],sc4[3],sh4[3]),0.f));
      }
      // ---- layer 2 ----
      f32x4 acc2[4];
      #pragma unroll
      for (int tc=0;tc<4;tc++) acc2[tc]=zero4();
      #pragma unroll
      for (int kc=0;kc<2;kc++){
        f16x8 Bf = *(const f16x8*)&Xs[colbase + kc*16 + q*4];
        #pragma unroll
        for (int tc=0;tc<4;tc++){
          f16x8 Af = *(const f16x8*)&Wf2[((tc*2+kc)*64+lane)*4];
          acc2[tc] = MFMA16(Af,Bf,acc2[tc]);
        }
      }
      if constexpr (STAGE==1){
        #pragma unroll
        for (int tc=0;tc<4;tc++){
          #pragma unroll
          for (int r=0;r<4;r++){
            float s1=acc2[tc][r], s2=__fmul_rn(s1,s1);
            #pragma unroll
            for (int off=1;off<16;off<<=1){ s1+=__shfl_xor(s1,off); s2+=__shfl_xor(s2,off); }
            if (n==0){ const int c=tc*16+q*4+r;
              atomicAdd(&bins[c], s1); atomicAdd(&bins[TCO+c], s2); }
          }
        }
      } else {
        #pragma unroll
        for (int tc=0;tc<4;tc++){
          const f32x4 sc4 = *(const f32x4*)&affine[256+tc*16+q*4];
          const f32x4 sh4 = *(const f32x4*)&affine[256+128+tc*16+q*4];
          Xs[colbase + tc*8+q*2]   = packh(fmaxf(fmaf(acc2[tc][0],sc4[0],sh4[0]),0.f),
                                           fmaxf(fmaf(acc2[tc][1],sc4[1],sh4[1]),0.f));
          Xs[colbase + tc*8+q*2+1] = packh(fmaxf(fmaf(acc2[tc][2],sc4[2],sh4[2]),0.f),
                                           fmaxf(fmaf(acc2[tc][3],sc4[3],sh4[3]),0.f));
        }
        // ---- layer 3 (128 ch) ----
        f32x4 acc3[8];
        #pragma unroll
        for (int tc=0;tc<8;tc++) acc3[tc]=zero4();
        #pragma unroll
        for (int kc=0;kc<2;kc++){
          f16x8 Bf = *(const f16x8*)&Xs[colbase + kc*16 + q*4];
          #pragma unroll
          for (int tc=0;tc<8;tc++){
            f16x8 Af = *(const f16x8*)&Wf3[((tc*2+kc)*64+lane)*4];
            acc3[tc] = MFMA16(Af,Bf,acc3[tc]);
          }
        }
        u32* mmb = &mm[(ch&1)*512];
        #pragma unroll
        for (int tc=0;tc<8;tc++){
          #pragma unroll
          for (int r=0;r<4;r++){
            float y=acc3[tc][r];
            float s1=y, s2=__fmul_rn(y,y);
            u32 pm = packh(y, -y);                       // (max, -min) carrier
            #pragma unroll
            for (int off=1;off<16;off<<=1){
              s1+=__shfl_xor(s1,off); s2+=__shfl_xor(s2,off);
              u32 o = (u32)__shfl_xor((int)pm,off);
              pm = asU32(__builtin_elementwise_max(asH2(pm), asH2(o)));
            }
            if (n==0){ const int c=tc*16+q*4+r;
              atomicAdd(&bins[c], s1); atomicAdd(&bins[128+c], s2);
              mmb[w*128+c]=pm; }
          }
        }
        __syncthreads();                                 // mm panel ready
        {
          const int c = t&127, gg = t>>7;                // 2 groups of 32 per chunk
          u32 a = mmb[(2*gg)*128+c], b2 = mmb[(2*gg+1)*128+c];
          h2v hm = __builtin_elementwise_max(asH2(a), asH2(b2));
          const int s0 = ((blockIdx.x*8 + ch*2) & (NS-1)) + gg;
          outMM[((size_t)b*128+c)*NS + s0] = packh((float)hm[0], -(float)hm[1]);
        }
      }
    }
  }

  __syncthreads();
  if (t < TCO){
    atomicAdd(&stats[STAGE*256 + 2*t],   bins[t]);
    atomicAdd(&stats[STAGE*256 + 2*t+1], bins[TCO+t]);
  }
}

// ----------------------------------------------------------- finalize ----
// affine SoA per layer: af[c]=scale, af[128+c]=shift
__global__ void finalize_kernel(const float* __restrict__ st, float* __restrict__ af,
                                const float* __restrict__ gamma, const float* __restrict__ beta, int C)
{
  int c = threadIdx.x;
  if (c < C){
    float mean = st[2*c] * (1.f/524288.f);
    float var  = fmaxf(st[2*c+1] * (1.f/524288.f) - mean*mean, 0.f);
    float rstd = 1.f / sqrtf(var + 1e-5f);
    float sc = rstd * gamma[c];
    af[c]     = sc;
    af[128+c] = beta[c] - mean*sc;
  }
}

// -------------------------------------------------------------- apply ----
__global__ void apply_kernel(const float* __restrict__ affine, float* __restrict__ outF)
{
  const int i = blockIdx.x*256 + threadIdx.x;      // 16*128*1024 elements
  const int c = (i >> 10) & 127;
  u32 v = ((const u32*)outF)[i];
  h2v h = asH2(v);
  float sc = affine[512+c], sh = affine[512+128+c];
  float cand = (sc > 0.f) ? (float)h[0] : (float)h[1];
  outF[i] = fmaxf(fmaf(cand, sc, sh), 0.f);
}

// ------------------------------------------------------------- launch ----
extern "C" void kernel_launch(void* const* d_in, const int* in_sizes, int n_in,
                              void* d_out, int out_size, void* d_ws, size_t ws_size,
                              hipStream_t stream)
{
  (void)in_sizes; (void)n_in; (void)out_size; (void)ws_size;
  const float* xyz  = (const float*)d_in[0];
  const float* feat = (const float*)d_in[1];
  const float* W0 = (const float*)d_in[2];
  const float* g0 = (const float*)d_in[3];
  const float* b0 = (const float*)d_in[4];
  const float* W1 = (const float*)d_in[5];
  const float* g1 = (const float*)d_in[6];
  const float* b1 = (const float*)d_in[7];
  const float* W2 = (const float*)d_in[8];
  const float* g2 = (const float*)d_in[9];
  const float* b2 = (const float*)d_in[10];

  char* ws = (char*)d_ws;                      // 1,087,488 B total (< proven 1,088,512)
  u16*   gidx    = (u16*)  (ws + 0);           // 524288 u16  = 1048576 B
  u32*   Wf1     = (u32*)  (ws + 1048576);     // 2048 u32    =    8192 B
  u32*   Wf2     = (u32*)  (ws + 1056768);     // 2048 u32    =    8192 B
  u32*   Wf3     = (u32*)  (ws + 1064960);     // 4096 u32    =   16384 B
  float* stats   = (float*)(ws + 1081344);     // 768 f32     =    3072 B
  float* affine  = (float*)(ws + 1084416);     // 768 f32     =    3072 B

  float* out_xyz  = (float*)d_out;                         // (16,3,1024) f32
  float* out_feat = (float*)d_out + (size_t)NB*3*NS;       // (16,128,1024) f32

  prep_kernel<<<1,256,0,stream>>>(W0,W1,W2,Wf1,Wf2,Wf3,stats);
  fps_kernel<<<NB,1024,0,stream>>>(xyz, out_xyz);
  ballq_kernel<<<NB*NS/4,256,0,stream>>>(xyz, out_xyz, gidx);

  mlp_pass<0><<<NSAMP/256,256,0,stream>>>(xyz,feat,out_xyz,gidx,Wf1,Wf2,Wf3,W0,affine,stats,(u32*)out_feat);
  finalize_kernel<<<1,128,0,stream>>>(stats,     affine,     g0,b0, 64);
  mlp_pass<1><<<NSAMP/256,256,0,stream>>>(xyz,feat,out_xyz,gidx,Wf1,Wf2,Wf3,W0,affine,stats,(u32*)out_feat);
  finalize_kernel<<<1,128,0,stream>>>(stats+256, affine+256, g1,b1, 64);
  mlp_pass<2><<<NSAMP/256,256,0,stream>>>(xyz,feat,out_xyz,gidx,Wf1,Wf2,Wf3,W0,affine,stats,(u32*)out_feat);
  finalize_kernel<<<1,128,0,stream>>>(stats+512, affine+512, g2,b2, 128);
  apply_kernel<<<(NB*128*NS)/256,256,0,stream>>>(affine, out_feat);
}